// Round 1
// baseline (764.111 us; speedup 1.0000x reference)
//
#include <hip/hip_runtime.h>
#include <stdint.h>

typedef __bf16 bf16_t;
typedef bf16_t bf16x8 __attribute__((ext_vector_type(8)));
typedef float f32x4 __attribute__((ext_vector_type(4)));
typedef unsigned int u32;
typedef unsigned short u16;

#define DEV_INLINE __device__ __forceinline__

// ---------- constants ----------
#define S_LEN 2048
#define D_MODEL 4096
#define HQ 32
#define HK 8
#define HD 128

DEV_INLINE u16 f2bf(float x) {
  union { float f; uint32_t u; } v; v.f = x;
  uint32_t r = v.u + 0x7FFFu + ((v.u >> 16) & 1u);  // RNE
  return (u16)(r >> 16);
}

DEV_INLINE void async_load16(const void* g, void* l) {
  __builtin_amdgcn_global_load_lds(
      (const __attribute__((address_space(1))) u32*)g,
      (__attribute__((address_space(3))) u32*)l, 16, 0, 0);
}

DEV_INLINE f32x4 mfma16(bf16x8 a, bf16x8 b, f32x4 c) {
  return __builtin_amdgcn_mfma_f32_16x16x32_bf16(a, b, c, 0, 0, 0);
}

// ---------- elementwise f32 -> bf16 ----------
__global__ void cvt_f32_bf16(const float* __restrict__ in, u16* __restrict__ out, int n) {
  int i = (blockIdx.x * blockDim.x + threadIdx.x) * 4;
  if (i >= n) return;
  float4 v = *(const float4*)(in + i);
  union { u16 s[4]; uint2 u; } o;
  o.s[0] = f2bf(v.x); o.s[1] = f2bf(v.y); o.s[2] = f2bf(v.z); o.s[3] = f2bf(v.w);
  *(uint2*)(out + i) = o.u;
}

// ---------- transpose fp32 (R,C) -> bf16 (C,R) ----------
__global__ void transpose_f32_bf16(const float* __restrict__ in, u16* __restrict__ out,
                                   int R, int C) {
  __shared__ float tile[32][33];
  int tx = threadIdx.x, ty = threadIdx.y;           // block (32,8)
  int c0 = blockIdx.x * 32, r0 = blockIdx.y * 32;
#pragma unroll
  for (int i = 0; i < 4; ++i)
    tile[ty + i * 8][tx] = in[(long)(r0 + ty + i * 8) * C + c0 + tx];
  __syncthreads();
#pragma unroll
  for (int i = 0; i < 4; ++i)
    out[(long)(c0 + ty + i * 8) * R + r0 + tx] = f2bf(tile[tx][ty + i * 8]);
}

// ---------- RoPE (interleaved pairs) + bf16 cast; scale folded in ----------
__global__ void rope_cvt(const float* __restrict__ in, const float* __restrict__ cosb,
                         const float* __restrict__ sinb, u16* __restrict__ out,
                         int H, float scale) {
  int idx = blockIdx.x * blockDim.x + threadIdx.x;   // over S*H*64
  int j = idx & 63;
  int sh = idx >> 6;            // s*H + h
  int s = sh / H;
  long base = (long)sh * HD;
  float q0 = in[base + 2 * j], q1 = in[base + 2 * j + 1];
  float c = cosb[s * 64 + j], sn = sinb[s * 64 + j];
  out[base + 2 * j]     = f2bf((q0 * c - q1 * sn) * scale);
  out[base + 2 * j + 1] = f2bf((q0 * sn + q1 * c) * scale);
}

// ---------- GEMM: C(M,N) f32 = A(M,K) bf16 @ Bt(N,K)^T bf16 ----------
// m97 structure: 128x128 tile, BK=32, 256 thr (4 waves, 2x2 of 64x64),
// global_load_lds width 16, XOR chunk swizzle in LDS.
__global__ __launch_bounds__(256) void gemm_bt(
    const u16* __restrict__ A, const u16* __restrict__ Bt, float* __restrict__ C,
    int M, int N, int K) {
  __shared__ __attribute__((aligned(16))) u16 As[128 * 32];
  __shared__ __attribute__((aligned(16))) u16 Bs[128 * 32];
  const int tid = threadIdx.x;
  const int lane = tid & 63, wave = tid >> 6;
  const int quad = lane >> 4, l15 = lane & 15;
  const int bm = blockIdx.y, bn = blockIdx.x;
  const int wr = (wave >> 1) * 64, wc = (wave & 1) * 64;
  const long arow = (long)bm * 128, brow = (long)bn * 128;

  f32x4 acc[4][4] = {};

  for (int k0 = 0; k0 < K; k0 += 32) {
#pragma unroll
    for (int t = 0; t < 2; ++t) {
      int c = tid + t * 256;            // 512 chunks of 16B per 8KB tile
      int row = c >> 2, cc = c & 3;
      int csrc = cc ^ (row & 3);
      async_load16(A + (arow + row) * K + k0 + csrc * 8, (u16*)As + c * 8);
      async_load16(Bt + (brow + row) * K + k0 + csrc * 8, (u16*)Bs + c * 8);
    }
    __syncthreads();
    bf16x8 af[4], bfr[4];
#pragma unroll
    for (int i = 0; i < 4; ++i) {
      int row = wr + i * 16 + l15;
      af[i] = *(const bf16x8*)(As + row * 32 + ((quad ^ (row & 3)) * 8));
    }
#pragma unroll
    for (int j = 0; j < 4; ++j) {
      int row = wc + j * 16 + l15;
      bfr[j] = *(const bf16x8*)(Bs + row * 32 + ((quad ^ (row & 3)) * 8));
    }
#pragma unroll
    for (int i = 0; i < 4; ++i)
#pragma unroll
      for (int j = 0; j < 4; ++j)
        acc[i][j] = mfma16(af[i], bfr[j], acc[i][j]);
    __syncthreads();
  }
#pragma unroll
  for (int i = 0; i < 4; ++i) {
    int row = bm * 128 + wr + i * 16 + quad * 4;
#pragma unroll
    for (int j = 0; j < 4; ++j) {
      int col = bn * 128 + wc + j * 16 + l15;
#pragma unroll
      for (int r = 0; r < 4; ++r)
        C[(long)(row + r) * N + col] = acc[i][j][r];
    }
  }
}

// ---------- flash attention ----------
// grid (S/128, HQ); 512 thr = 8 waves; wave w owns q rows [128*t + 16w, +16)
// Qb: (S, HQ*HD) bf16 roped*scale ; Kb: (S, HK*HD) bf16 roped
// Vt: (HK*HD, S) bf16 ; Ob: (S, HQ*HD) bf16
#define NEG_INF -1e30f
__global__ __launch_bounds__(512) void attn_fwd(
    const u16* __restrict__ Qb, const u16* __restrict__ Kb,
    const u16* __restrict__ Vt, u16* __restrict__ Ob) {
  __shared__ __attribute__((aligned(16))) u16 KVs[128 * 128];  // K then V (aliased)
  __shared__ __attribute__((aligned(16))) u16 Ps[8][16 * 128]; // per-wave P
  const int tid = threadIdx.x;
  const int lane = tid & 63, wave = tid >> 6;
  const int quad = lane >> 4, l15 = lane & 15;
  const int t = blockIdx.x, h = blockIdx.y;
  const int hk = h >> 2;

  // Q fragments (A-operand: m=l15, k=quad*8.. ; 4 k-steps over HD=128)
  bf16x8 qf[4];
  {
    const u16* qrow = Qb + (long)(t * 128 + wave * 16 + l15) * (HQ * HD) + h * HD + quad * 8;
#pragma unroll
    for (int ks = 0; ks < 4; ++ks) qf[ks] = *(const bf16x8*)(qrow + ks * 32);
  }

  float m_run[4], l_run[4];
#pragma unroll
  for (int r = 0; r < 4; ++r) { m_run[r] = NEG_INF; l_run[r] = 0.f; }
  f32x4 oacc[8] = {};

  for (int j = 0; j <= t; ++j) {
    // ---- stage K tile (128 kpos x 128 d), swizzled ----
#pragma unroll
    for (int it = 0; it < 4; ++it) {
      int c = tid + it * 512;           // 2048 chunks
      int row = c >> 4, cc = c & 15, csrc = cc ^ (row & 15);
      async_load16(Kb + (long)(j * 128 + row) * (HK * HD) + hk * HD + csrc * 8,
                   (u16*)KVs + c * 8);
    }
    __syncthreads();

    // ---- scores: Q @ K^T ----
    f32x4 sc[8] = {};
#pragma unroll
    for (int ks = 0; ks < 4; ++ks)
#pragma unroll
      for (int tj = 0; tj < 8; ++tj) {
        int row = tj * 16 + l15;
        bf16x8 kf = *(const bf16x8*)(KVs + row * 128 + (((ks * 4 + quad) ^ (row & 15)) * 8));
        sc[tj] = mfma16(qf[ks], kf, sc[tj]);
      }

    // ---- online softmax (rows live in 16-lane groups) ----
    const bool diag = (j == t);
#pragma unroll
    for (int r = 0; r < 4; ++r) {
      int qloc = wave * 16 + quad * 4 + r;
      if (diag) {
#pragma unroll
        for (int tj = 0; tj < 8; ++tj)
          if (tj * 16 + l15 > qloc) sc[tj][r] = NEG_INF;
      }
      float m = sc[0][r];
#pragma unroll
      for (int tj = 1; tj < 8; ++tj) m = fmaxf(m, sc[tj][r]);
#pragma unroll
      for (int off = 1; off < 16; off <<= 1) m = fmaxf(m, __shfl_xor(m, off));
      float mnew = fmaxf(m_run[r], m);
      float alpha = __expf(m_run[r] - mnew);
      m_run[r] = mnew;
      float rs = 0.f;
#pragma unroll
      for (int tj = 0; tj < 8; ++tj) {
        float p = __expf(sc[tj][r] - mnew);
        sc[tj][r] = p;
        rs += p;
      }
#pragma unroll
      for (int off = 1; off < 16; off <<= 1) rs += __shfl_xor(rs, off);
      l_run[r] = l_run[r] * alpha + rs;
#pragma unroll
      for (int tj = 0; tj < 8; ++tj) oacc[tj][r] *= alpha;
    }

    // ---- P -> LDS (C-layout -> A-layout round trip), per-wave region ----
    u16* pw = &Ps[wave][0];
#pragma unroll
    for (int tj = 0; tj < 8; ++tj)
#pragma unroll
      for (int r = 0; r < 4; ++r) {
        int prow = quad * 4 + r;
        int col = tj * 16 + l15;
        pw[prow * 128 + (((col >> 3) ^ prow) * 8) + (col & 7)] = f2bf(sc[tj][r]);
      }
    __syncthreads();   // all waves done reading K before V overwrites

    // ---- stage V^T tile (128 d x 128 kpos), swizzled ----
#pragma unroll
    for (int it = 0; it < 4; ++it) {
      int c = tid + it * 512;
      int row = c >> 4, cc = c & 15, csrc = cc ^ (row & 15);
      async_load16(Vt + (long)(hk * HD + row) * S_LEN + j * 128 + csrc * 8,
                   (u16*)KVs + c * 8);
    }
    __syncthreads();

    // ---- O += P @ V ----
#pragma unroll
    for (int ks = 0; ks < 4; ++ks) {
      bf16x8 pf = *(const bf16x8*)(pw + l15 * 128 + (((ks * 4 + quad) ^ l15) * 8));
#pragma unroll
      for (int tj = 0; tj < 8; ++tj) {
        int row = tj * 16 + l15;
        bf16x8 vf = *(const bf16x8*)(KVs + row * 128 + (((ks * 4 + quad) ^ (row & 15)) * 8));
        oacc[tj] = mfma16(pf, vf, oacc[tj]);
      }
    }
    __syncthreads();   // done with V before next iteration stages K
  }

  // ---- epilogue: normalize, write bf16 ----
#pragma unroll
  for (int tj = 0; tj < 8; ++tj)
#pragma unroll
    for (int r = 0; r < 4; ++r) {
      int grow = t * 128 + wave * 16 + quad * 4 + r;
      int gcol = h * HD + tj * 16 + l15;
      Ob[(long)grow * (HQ * HD) + gcol] = f2bf(oacc[tj][r] / l_run[r]);
    }
}

// ---------- host ----------
#define MB (1024L * 1024L)

extern "C" void kernel_launch(void* const* d_in, const int* in_sizes, int n_in,
                              void* d_out, int out_size, void* d_ws, size_t ws_size,
                              hipStream_t stream) {
  const float* x    = (const float*)d_in[0];
  const float* fcos = (const float*)d_in[1];
  const float* fsin = (const float*)d_in[2];
  const float* wq   = (const float*)d_in[3];
  const float* wk   = (const float*)d_in[4];
  const float* wv   = (const float*)d_in[5];
  const float* wo   = (const float*)d_in[6];
  float* out = (float*)d_out;

  char* ws = (char*)d_ws;
  u16*   wt    = (u16*)(ws + 0 * MB);     // 32 MB shared transposed-weight buffer
  u16*   xb    = (u16*)(ws + 32 * MB);    // 16 MB
  float* Qf    = (float*)(ws + 48 * MB);  // 32 MB
  float* Kf    = (float*)(ws + 80 * MB);  // 8 MB
  float* Vf    = (float*)(ws + 88 * MB);  // 8 MB
  u16*   Qb    = (u16*)(ws + 96 * MB);    // 16 MB
  u16*   Kb    = (u16*)(ws + 112 * MB);   // 4 MB
  u16*   Vt    = (u16*)(ws + 116 * MB);   // 4 MB
  u16*   attnb = (u16*)(ws + 120 * MB);   // 16 MB

  const int M = S_LEN, D = D_MODEL;

  // x -> bf16
  cvt_f32_bf16<<<(M * D) / 1024, 256, 0, stream>>>(x, xb, M * D);

  // Q = x @ wq
  transpose_f32_bf16<<<dim3(D / 32, D / 32), dim3(32, 8), 0, stream>>>(wq, wt, D, HQ * HD);
  gemm_bt<<<dim3((HQ * HD) / 128, M / 128), 256, 0, stream>>>(xb, wt, Qf, M, HQ * HD, D);
  // K = x @ wk
  transpose_f32_bf16<<<dim3((HK * HD) / 32, D / 32), dim3(32, 8), 0, stream>>>(wk, wt, D, HK * HD);
  gemm_bt<<<dim3((HK * HD) / 128, M / 128), 256, 0, stream>>>(xb, wt, Kf, M, HK * HD, D);
  // V = x @ wv
  transpose_f32_bf16<<<dim3((HK * HD) / 32, D / 32), dim3(32, 8), 0, stream>>>(wv, wt, D, HK * HD);
  gemm_bt<<<dim3((HK * HD) / 128, M / 128), 256, 0, stream>>>(xb, wt, Vf, M, HK * HD, D);

  // RoPE + bf16 (scale folded into Q)
  rope_cvt<<<(M * HQ * 64) / 256, 256, 0, stream>>>(Qf, fcos, fsin, Qb, HQ, 0.08838834764831845f);
  rope_cvt<<<(M * HK * 64) / 256, 256, 0, stream>>>(Kf, fcos, fsin, Kb, HK, 1.0f);
  // V^T
  transpose_f32_bf16<<<dim3((HK * HD) / 32, M / 32), dim3(32, 8), 0, stream>>>(Vf, Vt, M, HK * HD);

  // flash attention
  attn_fwd<<<dim3(M / 128, HQ), 512, 0, stream>>>(Qb, Kb, Vt, attnb);

  // out = attn @ wo
  transpose_f32_bf16<<<dim3(D / 32, D / 32), dim3(32, 8), 0, stream>>>(wo, wt, HQ * HD, D);
  gemm_bt<<<dim3(D / 128, M / 128), 256, 0, stream>>>(attnb, wt, out, M, D, HQ * HD);
}

// Round 2
// 729.296 us; speedup vs baseline: 1.0477x; 1.0477x over previous
//
#include <hip/hip_runtime.h>
#include <stdint.h>

typedef __bf16 bf16_t;
typedef bf16_t bf16x8 __attribute__((ext_vector_type(8)));
typedef float f32x4 __attribute__((ext_vector_type(4)));
typedef unsigned int u32;
typedef unsigned short u16;

#define DEV_INLINE __device__ __forceinline__

// ---------- constants ----------
#define S_LEN 2048
#define D_MODEL 4096
#define HQ 32
#define HK 8
#define HD 128
#define NQKV 6144   // HQ*HD + 2*HK*HD

DEV_INLINE u16 f2bf(float x) {
  union { float f; uint32_t u; } v; v.f = x;
  uint32_t r = v.u + 0x7FFFu + ((v.u >> 16) & 1u);  // RNE
  return (u16)(r >> 16);
}
DEV_INLINE float bf2f(u16 x) {
  union { uint32_t u; float f; } v; v.u = ((uint32_t)x) << 16;
  return v.f;
}

DEV_INLINE void async_load16(const void* g, void* l) {
  __builtin_amdgcn_global_load_lds(
      (const __attribute__((address_space(1))) u32*)g,
      (__attribute__((address_space(3))) u32*)l, 16, 0, 0);
}

DEV_INLINE f32x4 mfma16(bf16x8 a, bf16x8 b, f32x4 c) {
  return __builtin_amdgcn_mfma_f32_16x16x32_bf16(a, b, c, 0, 0, 0);
}

// ---------- elementwise f32 -> bf16 ----------
__global__ void cvt_f32_bf16(const float* __restrict__ in, u16* __restrict__ out, int n) {
  int i = (blockIdx.x * blockDim.x + threadIdx.x) * 4;
  if (i >= n) return;
  float4 v = *(const float4*)(in + i);
  union { u16 s[4]; uint2 u; } o;
  o.s[0] = f2bf(v.x); o.s[1] = f2bf(v.y); o.s[2] = f2bf(v.z); o.s[3] = f2bf(v.w);
  *(uint2*)(out + i) = o.u;
}

// ---------- transpose fp32 (R,C) -> bf16 (C,R) ----------
__global__ void transpose_f32_bf16(const float* __restrict__ in, u16* __restrict__ out,
                                   int R, int C) {
  __shared__ float tile[32][33];
  int tx = threadIdx.x, ty = threadIdx.y;           // block (32,8)
  int c0 = blockIdx.x * 32, r0 = blockIdx.y * 32;
#pragma unroll
  for (int i = 0; i < 4; ++i)
    tile[ty + i * 8][tx] = in[(long)(r0 + ty + i * 8) * C + c0 + tx];
  __syncthreads();
#pragma unroll
  for (int i = 0; i < 4; ++i)
    out[(long)(c0 + ty + i * 8) * R + r0 + tx] = f2bf(tile[tx][ty + i * 8]);
}

// ---------- transpose bf16 (R, ld_in cols, slice [col_off, col_off+C)) -> (C, R) ----------
__global__ void transpose_bf16(const u16* __restrict__ in, u16* __restrict__ out,
                               int R, int C, int ld_in, int col_off) {
  __shared__ u16 tile[32][33];
  int tx = threadIdx.x, ty = threadIdx.y;           // block (32,8)
  int c0 = blockIdx.x * 32, r0 = blockIdx.y * 32;
#pragma unroll
  for (int i = 0; i < 4; ++i)
    tile[ty + i * 8][tx] = in[(long)(r0 + ty + i * 8) * ld_in + col_off + c0 + tx];
  __syncthreads();
#pragma unroll
  for (int i = 0; i < 4; ++i)
    out[(long)(c0 + ty + i * 8) * R + r0 + tx] = tile[tx][ty + i * 8];
}

// ---------- RoPE on bf16 (strided input slice) -> packed bf16 ----------
__global__ void rope_bf16(const u16* __restrict__ in, const float* __restrict__ cosb,
                          const float* __restrict__ sinb, u16* __restrict__ out,
                          int H, int ld_in, int col_off, float scale) {
  int idx = blockIdx.x * blockDim.x + threadIdx.x;   // over S*H*64
  int j = idx & 63;
  int sh = idx >> 6;            // s*H + h
  int s = sh / H, h = sh - s * H;
  const u16* ip = in + (long)s * ld_in + col_off + h * HD;
  union { u32 u; u16 s2[2]; } v; v.u = *(const u32*)(ip + 2 * j);
  float q0 = bf2f(v.s2[0]), q1 = bf2f(v.s2[1]);
  float c = cosb[s * 64 + j], sn = sinb[s * 64 + j];
  union { u16 s2[2]; u32 u; } o;
  o.s2[0] = f2bf((q0 * c - q1 * sn) * scale);
  o.s2[1] = f2bf((q0 * sn + q1 * c) * scale);
  *(u32*)(out + (long)sh * HD + 2 * j) = o.u;
}

// ---------- GEMM core: 128x128 tile, BK=32, 4 waves ----------
#define GEMM_BODY(STORE)                                                        \
  __shared__ __attribute__((aligned(16))) u16 As[128 * 32];                     \
  __shared__ __attribute__((aligned(16))) u16 Bs[128 * 32];                     \
  const int tid = threadIdx.x;                                                  \
  const int lane = tid & 63, wave = tid >> 6;                                   \
  const int quad = lane >> 4, l15 = lane & 15;                                  \
  const int bm = blockIdx.y, bn = blockIdx.x;                                   \
  const int wr = (wave >> 1) * 64, wc = (wave & 1) * 64;                        \
  const long arow = (long)bm * 128, brow = (long)bn * 128;                      \
  f32x4 acc[4][4] = {};                                                         \
  for (int k0 = 0; k0 < K; k0 += 32) {                                          \
    _Pragma("unroll")                                                           \
    for (int t = 0; t < 2; ++t) {                                               \
      int c = tid + t * 256;                                                    \
      int row = c >> 2, cc = c & 3;                                             \
      int csrc = cc ^ (row & 3);                                                \
      async_load16(A + (arow + row) * K + k0 + csrc * 8, (u16*)As + c * 8);     \
      async_load16(Bt + (brow + row) * K + k0 + csrc * 8, (u16*)Bs + c * 8);    \
    }                                                                           \
    __syncthreads();                                                            \
    bf16x8 af[4], bfr[4];                                                       \
    _Pragma("unroll")                                                           \
    for (int i = 0; i < 4; ++i) {                                               \
      int row = wr + i * 16 + l15;                                              \
      af[i] = *(const bf16x8*)(As + row * 32 + ((quad ^ (row & 3)) * 8));       \
    }                                                                           \
    _Pragma("unroll")                                                           \
    for (int j = 0; j < 4; ++j) {                                               \
      int row = wc + j * 16 + l15;                                              \
      bfr[j] = *(const bf16x8*)(Bs + row * 32 + ((quad ^ (row & 3)) * 8));      \
    }                                                                           \
    _Pragma("unroll")                                                           \
    for (int i = 0; i < 4; ++i)                                                 \
      _Pragma("unroll")                                                         \
      for (int j = 0; j < 4; ++j)                                               \
        acc[i][j] = mfma16(af[i], bfr[j], acc[i][j]);                           \
    __syncthreads();                                                            \
  }                                                                             \
  _Pragma("unroll")                                                             \
  for (int i = 0; i < 4; ++i) {                                                 \
    int row = bm * 128 + wr + i * 16 + quad * 4;                                \
    _Pragma("unroll")                                                           \
    for (int j = 0; j < 4; ++j) {                                               \
      int col = bn * 128 + wc + j * 16 + l15;                                   \
      _Pragma("unroll")                                                         \
      for (int r = 0; r < 4; ++r) STORE;                                        \
    }                                                                           \
  }

// C(M,N) f32 = A(M,K)bf16 @ Bt(N,K)^T
__global__ __launch_bounds__(256) void gemm_bt(
    const u16* __restrict__ A, const u16* __restrict__ Bt, float* __restrict__ C,
    int M, int N, int K) {
  GEMM_BODY(C[(long)(row + r) * N + col] = acc[i][j][r])
}

// C(M,N) bf16 = A(M,K)bf16 @ Bt(N,K)^T
__global__ __launch_bounds__(256) void gemm_bt_bf16(
    const u16* __restrict__ A, const u16* __restrict__ Bt, u16* __restrict__ C,
    int M, int N, int K) {
  GEMM_BODY(C[(long)(row + r) * N + col] = f2bf(acc[i][j][r]))
}

// ---------- flash attention ----------
// grid (32, HQ); 256 thr = 4 waves; q-tile 64 rows, heavy-first (u = 31 - bx)
// wave w owns q rows [64*u + 16w, +16)
// Qb: (S, HQ*HD) bf16 roped*scale ; Kb: (S, HK*HD) bf16 roped
// Vt: (HK*HD, S) bf16 ; Ob: (S, HQ*HD) bf16
#define NEG_INF -1e30f
__global__ __launch_bounds__(256) void attn_fwd(
    const u16* __restrict__ Qb, const u16* __restrict__ Kb,
    const u16* __restrict__ Vt, u16* __restrict__ Ob) {
  __shared__ __attribute__((aligned(16))) u16 KVs[128 * 128];  // K then V (aliased)
  __shared__ __attribute__((aligned(16))) u16 Ps[4][16 * 128]; // per-wave P
  const int tid = threadIdx.x;
  const int lane = tid & 63, wave = tid >> 6;
  const int quad = lane >> 4, l15 = lane & 15;
  const int u = 31 - blockIdx.x;        // heavy tiles dispatch first
  const int h = blockIdx.y;
  const int hk = h >> 2;
  const int jmax = u >> 1;

  // Q fragments (A-operand: m=l15, k=quad*8.. ; 4 k-steps over HD=128)
  bf16x8 qf[4];
  {
    const u16* qrow = Qb + (long)(u * 64 + wave * 16 + l15) * (HQ * HD) + h * HD + quad * 8;
#pragma unroll
    for (int ks = 0; ks < 4; ++ks) qf[ks] = *(const bf16x8*)(qrow + ks * 32);
  }

  float m_run[4], l_run[4];
#pragma unroll
  for (int r = 0; r < 4; ++r) { m_run[r] = NEG_INF; l_run[r] = 0.f; }
  f32x4 oacc[8] = {};

  for (int j = 0; j <= jmax; ++j) {
    // ---- stage K tile (128 kpos x 128 d), swizzled ----
#pragma unroll
    for (int it = 0; it < 8; ++it) {
      int c = tid + it * 256;           // 2048 chunks
      int row = c >> 4, cc = c & 15, csrc = cc ^ (row & 15);
      async_load16(Kb + (long)(j * 128 + row) * (HK * HD) + hk * HD + csrc * 8,
                   (u16*)KVs + c * 8);
    }
    __syncthreads();

    // ---- scores: Q @ K^T ----
    f32x4 sc[8] = {};
#pragma unroll
    for (int ks = 0; ks < 4; ++ks)
#pragma unroll
      for (int tj = 0; tj < 8; ++tj) {
        int row = tj * 16 + l15;
        bf16x8 kf = *(const bf16x8*)(KVs + row * 128 + (((ks * 4 + quad) ^ (row & 15)) * 8));
        sc[tj] = mfma16(qf[ks], kf, sc[tj]);
      }

    // ---- online softmax (rows live in 16-lane groups) ----
    const bool diag = (j == jmax);
#pragma unroll
    for (int r = 0; r < 4; ++r) {
      if (diag) {
        int qglob = u * 64 + wave * 16 + quad * 4 + r;
#pragma unroll
        for (int tj = 0; tj < 8; ++tj)
          if (j * 128 + tj * 16 + l15 > qglob) sc[tj][r] = NEG_INF;
      }
      float m = sc[0][r];
#pragma unroll
      for (int tj = 1; tj < 8; ++tj) m = fmaxf(m, sc[tj][r]);
#pragma unroll
      for (int off = 1; off < 16; off <<= 1) m = fmaxf(m, __shfl_xor(m, off));
      float mnew = fmaxf(m_run[r], m);
      float alpha = __expf(m_run[r] - mnew);
      m_run[r] = mnew;
      float rs = 0.f;
#pragma unroll
      for (int tj = 0; tj < 8; ++tj) {
        float p = __expf(sc[tj][r] - mnew);
        sc[tj][r] = p;
        rs += p;
      }
#pragma unroll
      for (int off = 1; off < 16; off <<= 1) rs += __shfl_xor(rs, off);
      l_run[r] = l_run[r] * alpha + rs;
#pragma unroll
      for (int tj = 0; tj < 8; ++tj) oacc[tj][r] *= alpha;
    }

    // ---- P -> LDS (C-layout -> A-layout round trip), per-wave region ----
    u16* pw = &Ps[wave][0];
#pragma unroll
    for (int tj = 0; tj < 8; ++tj)
#pragma unroll
      for (int r = 0; r < 4; ++r) {
        int prow = quad * 4 + r;
        int col = tj * 16 + l15;
        pw[prow * 128 + (((col >> 3) ^ prow) * 8) + (col & 7)] = f2bf(sc[tj][r]);
      }
    __syncthreads();   // all waves done reading K before V overwrites

    // ---- stage V^T tile (128 d x 128 kpos), swizzled ----
#pragma unroll
    for (int it = 0; it < 8; ++it) {
      int c = tid + it * 256;
      int row = c >> 4, cc = c & 15, csrc = cc ^ (row & 15);
      async_load16(Vt + (long)(hk * HD + row) * S_LEN + j * 128 + csrc * 8,
                   (u16*)KVs + c * 8);
    }
    __syncthreads();

    // ---- O += P @ V ----
#pragma unroll
    for (int ks = 0; ks < 4; ++ks) {
      bf16x8 pf = *(const bf16x8*)(pw + l15 * 128 + (((ks * 4 + quad) ^ l15) * 8));
#pragma unroll
      for (int tj = 0; tj < 8; ++tj) {
        int row = tj * 16 + l15;
        bf16x8 vf = *(const bf16x8*)(KVs + row * 128 + (((ks * 4 + quad) ^ (row & 15)) * 8));
        oacc[tj] = mfma16(pf, vf, oacc[tj]);
      }
    }
    __syncthreads();   // done with V before next iteration stages K
  }

  // ---- epilogue: normalize, write bf16 ----
#pragma unroll
  for (int tj = 0; tj < 8; ++tj)
#pragma unroll
    for (int r = 0; r < 4; ++r) {
      int grow = u * 64 + wave * 16 + quad * 4 + r;
      int gcol = h * HD + tj * 16 + l15;
      Ob[(long)grow * (HQ * HD) + gcol] = f2bf(oacc[tj][r] / l_run[r]);
    }
}

// ---------- host ----------
#define MB (1024L * 1024L)

extern "C" void kernel_launch(void* const* d_in, const int* in_sizes, int n_in,
                              void* d_out, int out_size, void* d_ws, size_t ws_size,
                              hipStream_t stream) {
  const float* x    = (const float*)d_in[0];
  const float* fcos = (const float*)d_in[1];
  const float* fsin = (const float*)d_in[2];
  const float* wq   = (const float*)d_in[3];
  const float* wk   = (const float*)d_in[4];
  const float* wv   = (const float*)d_in[5];
  const float* wo   = (const float*)d_in[6];
  float* out = (float*)d_out;

  char* ws = (char*)d_ws;
  u16* wt    = (u16*)(ws + 0 * MB);     // 48 MB: QKV weights^T (6144,4096); reused for wo^T
  u16* xb    = (u16*)(ws + 48 * MB);    // 16 MB
  u16* QKVb  = (u16*)(ws + 64 * MB);    // 24 MB: (S, 6144) bf16
  u16* Qb    = (u16*)(ws + 88 * MB);    // 16 MB
  u16* Kb    = (u16*)(ws + 104 * MB);   // 4 MB
  u16* Vt    = (u16*)(ws + 108 * MB);   // 4 MB
  u16* attnb = (u16*)(ws + 112 * MB);   // 16 MB

  const int M = S_LEN, D = D_MODEL;

  // x -> bf16
  cvt_f32_bf16<<<(M * D) / 1024, 256, 0, stream>>>(x, xb, M * D);

  // weights^T (concat rows: wq^T | wk^T | wv^T)
  transpose_f32_bf16<<<dim3(D / 32, D / 32), dim3(32, 8), 0, stream>>>(wq, wt, D, HQ * HD);
  transpose_f32_bf16<<<dim3((HK * HD) / 32, D / 32), dim3(32, 8), 0, stream>>>(
      wk, wt + (long)(HQ * HD) * D, D, HK * HD);
  transpose_f32_bf16<<<dim3((HK * HD) / 32, D / 32), dim3(32, 8), 0, stream>>>(
      wv, wt + (long)(HQ * HD + HK * HD) * D, D, HK * HD);

  // fused QKV projection -> bf16
  gemm_bt_bf16<<<dim3(NQKV / 128, M / 128), 256, 0, stream>>>(xb, wt, QKVb, M, NQKV, D);

  // RoPE (scale folded into Q) from QKV slices
  rope_bf16<<<(M * HQ * 64) / 256, 256, 0, stream>>>(
      QKVb, fcos, fsin, Qb, HQ, NQKV, 0, 0.08838834764831845f);
  rope_bf16<<<(M * HK * 64) / 256, 256, 0, stream>>>(
      QKVb, fcos, fsin, Kb, HK, NQKV, HQ * HD, 1.0f);
  // V^T from QKV slice
  transpose_bf16<<<dim3((HK * HD) / 32, M / 32), dim3(32, 8), 0, stream>>>(
      QKVb, Vt, M, HK * HD, NQKV, HQ * HD + HK * HD);

  // flash attention
  attn_fwd<<<dim3(32, HQ), 256, 0, stream>>>(Qb, Kb, Vt, attnb);

  // out = attn @ wo
  transpose_f32_bf16<<<dim3(D / 32, D / 32), dim3(32, 8), 0, stream>>>(wo, wt, HQ * HD, D);
  gemm_bt<<<dim3(D / 128, M / 128), 256, 0, stream>>>(attnb, wt, out, M, D, HQ * HD);
}

// Round 3
// 600.213 us; speedup vs baseline: 1.2731x; 1.2151x over previous
//
#include <hip/hip_runtime.h>
#include <stdint.h>

typedef __bf16 bf16_t;
typedef bf16_t bf16x8 __attribute__((ext_vector_type(8)));
typedef float f32x4 __attribute__((ext_vector_type(4)));
typedef unsigned int u32;
typedef unsigned short u16;

#define DEV_INLINE __device__ __forceinline__

// ---------- constants ----------
#define S_LEN 2048
#define D_MODEL 4096
#define HQ 32
#define HK 8
#define HD 128
#define NQKV 6144   // HQ*HD + 2*HK*HD

DEV_INLINE u16 f2bf(float x) {
  union { float f; uint32_t u; } v; v.f = x;
  uint32_t r = v.u + 0x7FFFu + ((v.u >> 16) & 1u);  // RNE
  return (u16)(r >> 16);
}
DEV_INLINE float bf2f(u16 x) {
  union { uint32_t u; float f; } v; v.u = ((uint32_t)x) << 16;
  return v.f;
}
DEV_INLINE u32 pack2bf(float a, float b) {
  return (u32)f2bf(a) | ((u32)f2bf(b) << 16);
}

DEV_INLINE void async_load16(const void* g, void* l) {
  __builtin_amdgcn_global_load_lds(
      (const __attribute__((address_space(1))) u32*)g,
      (__attribute__((address_space(3))) u32*)l, 16, 0, 0);
}

DEV_INLINE f32x4 mfma16(bf16x8 a, bf16x8 b, f32x4 c) {
  return __builtin_amdgcn_mfma_f32_16x16x32_bf16(a, b, c, 0, 0, 0);
}

// ---------- elementwise f32 -> bf16 ----------
__global__ void cvt_f32_bf16(const float* __restrict__ in, u16* __restrict__ out, int n) {
  int i = (blockIdx.x * blockDim.x + threadIdx.x) * 4;
  if (i >= n) return;
  float4 v = *(const float4*)(in + i);
  union { u16 s[4]; uint2 u; } o;
  o.s[0] = f2bf(v.x); o.s[1] = f2bf(v.y); o.s[2] = f2bf(v.z); o.s[3] = f2bf(v.w);
  *(uint2*)(out + i) = o.u;
}

// ---------- transpose fp32 (R,C) -> bf16 (C,R) ----------
__global__ void transpose_f32_bf16(const float* __restrict__ in, u16* __restrict__ out,
                                   int R, int C) {
  __shared__ float tile[32][33];
  int tx = threadIdx.x, ty = threadIdx.y;           // block (32,8)
  int c0 = blockIdx.x * 32, r0 = blockIdx.y * 32;
#pragma unroll
  for (int i = 0; i < 4; ++i)
    tile[ty + i * 8][tx] = in[(long)(r0 + ty + i * 8) * C + c0 + tx];
  __syncthreads();
#pragma unroll
  for (int i = 0; i < 4; ++i)
    out[(long)(c0 + ty + i * 8) * R + r0 + tx] = f2bf(tile[tx][ty + i * 8]);
}

// ---------- transpose bf16 (R, ld_in cols, slice [col_off, col_off+C)) -> (C, R) ----------
__global__ void transpose_bf16(const u16* __restrict__ in, u16* __restrict__ out,
                               int R, int C, int ld_in, int col_off) {
  __shared__ u16 tile[32][33];
  int tx = threadIdx.x, ty = threadIdx.y;           // block (32,8)
  int c0 = blockIdx.x * 32, r0 = blockIdx.y * 32;
#pragma unroll
  for (int i = 0; i < 4; ++i)
    tile[ty + i * 8][tx] = in[(long)(r0 + ty + i * 8) * ld_in + col_off + c0 + tx];
  __syncthreads();
#pragma unroll
  for (int i = 0; i < 4; ++i)
    out[(long)(c0 + ty + i * 8) * R + r0 + tx] = tile[tx][ty + i * 8];
}

// ---------- RoPE on bf16 (strided input slice) -> packed bf16 ----------
__global__ void rope_bf16(const u16* __restrict__ in, const float* __restrict__ cosb,
                          const float* __restrict__ sinb, u16* __restrict__ out,
                          int H, int ld_in, int col_off, float scale) {
  int idx = blockIdx.x * blockDim.x + threadIdx.x;   // over S*H*64
  int j = idx & 63;
  int sh = idx >> 6;            // s*H + h
  int s = sh / H, h = sh - s * H;
  const u16* ip = in + (long)s * ld_in + col_off + h * HD;
  union { u32 u; u16 s2[2]; } v; v.u = *(const u32*)(ip + 2 * j);
  float q0 = bf2f(v.s2[0]), q1 = bf2f(v.s2[1]);
  float c = cosb[s * 64 + j], sn = sinb[s * 64 + j];
  union { u16 s2[2]; u32 u; } o;
  o.s2[0] = f2bf((q0 * c - q1 * sn) * scale);
  o.s2[1] = f2bf((q0 * sn + q1 * c) * scale);
  *(u32*)(out + (long)sh * HD + 2 * j) = o.u;
}

// ---------- GEMM core: 128x128 tile, BK=32, 4 waves ----------
#define GEMM_BODY(STORE)                                                        \
  __shared__ __attribute__((aligned(16))) u16 As[128 * 32];                     \
  __shared__ __attribute__((aligned(16))) u16 Bs[128 * 32];                     \
  const int tid = threadIdx.x;                                                  \
  const int lane = tid & 63, wave = tid >> 6;                                   \
  const int quad = lane >> 4, l15 = lane & 15;                                  \
  const int bm = blockIdx.y, bn = blockIdx.x;                                   \
  const int wr = (wave >> 1) * 64, wc = (wave & 1) * 64;                        \
  const long arow = (long)bm * 128, brow = (long)bn * 128;                      \
  f32x4 acc[4][4] = {};                                                         \
  for (int k0 = 0; k0 < K; k0 += 32) {                                          \
    _Pragma("unroll")                                                           \
    for (int t = 0; t < 2; ++t) {                                               \
      int c = tid + t * 256;                                                    \
      int row = c >> 2, cc = c & 3;                                             \
      int csrc = cc ^ (row & 3);                                                \
      async_load16(A + (arow + row) * K + k0 + csrc * 8, (u16*)As + c * 8);     \
      async_load16(Bt + (brow + row) * K + k0 + csrc * 8, (u16*)Bs + c * 8);    \
    }                                                                           \
    __syncthreads();                                                            \
    bf16x8 af[4], bfr[4];                                                       \
    _Pragma("unroll")                                                           \
    for (int i = 0; i < 4; ++i) {                                               \
      int row = wr + i * 16 + l15;                                              \
      af[i] = *(const bf16x8*)(As + row * 32 + ((quad ^ (row & 3)) * 8));       \
    }                                                                           \
    _Pragma("unroll")                                                           \
    for (int j = 0; j < 4; ++j) {                                               \
      int row = wc + j * 16 + l15;                                              \
      bfr[j] = *(const bf16x8*)(Bs + row * 32 + ((quad ^ (row & 3)) * 8));      \
    }                                                                           \
    _Pragma("unroll")                                                           \
    for (int i = 0; i < 4; ++i)                                                 \
      _Pragma("unroll")                                                         \
      for (int j = 0; j < 4; ++j)                                               \
        acc[i][j] = mfma16(af[i], bfr[j], acc[i][j]);                           \
    __syncthreads();                                                            \
  }                                                                             \
  _Pragma("unroll")                                                             \
  for (int i = 0; i < 4; ++i) {                                                 \
    int row = bm * 128 + wr + i * 16 + quad * 4;                                \
    _Pragma("unroll")                                                           \
    for (int j = 0; j < 4; ++j) {                                               \
      int col = bn * 128 + wc + j * 16 + l15;                                   \
      _Pragma("unroll")                                                         \
      for (int r = 0; r < 4; ++r) STORE;                                        \
    }                                                                           \
  }

// C(M,N) f32 = A(M,K)bf16 @ Bt(N,K)^T
__global__ __launch_bounds__(256) void gemm_bt(
    const u16* __restrict__ A, const u16* __restrict__ Bt, float* __restrict__ C,
    int M, int N, int K) {
  GEMM_BODY(C[(long)(row + r) * N + col] = acc[i][j][r])
}

// C(M,N) bf16 = A(M,K)bf16 @ Bt(N,K)^T
__global__ __launch_bounds__(256) void gemm_bt_bf16(
    const u16* __restrict__ A, const u16* __restrict__ Bt, u16* __restrict__ C,
    int M, int N, int K) {
  GEMM_BODY(C[(long)(row + r) * N + col] = f2bf(acc[i][j][r]))
}

// ---------- flash attention (transposed formulation) ----------
// grid (16, HQ); 256 thr = 4 waves; q-tile 128, wave owns 32 q-rows (2 N-tiles).
// S^T = K @ Q^T (A=kf m->kpos, B=qf n->qrow); O^T = V^T @ P^T (A=vf m->d, B=pf n->qrow).
// P^T round-trips per-wave LDS: b64 writes (4 kpos/lane contiguous) -> b128 reads. No barrier.
// LDS: Ks 32KB + Vs 32KB + Pts 16KB = 80KB -> 2 blocks/CU.
#define NEG_INF -1e30f
__global__ __launch_bounds__(256, 2) void attn_fwd(
    const u16* __restrict__ Qb, const u16* __restrict__ Kb,
    const u16* __restrict__ Vt, u16* __restrict__ Ob) {
  __shared__ __attribute__((aligned(16))) u16 Ks[128 * 128];    // kpos-major
  __shared__ __attribute__((aligned(16))) u16 Vs[128 * 128];    // d-major (V^T)
  __shared__ __attribute__((aligned(16))) u16 Pts[4][16 * 128]; // per-wave P^T (qrow-major)
  const int tid = threadIdx.x;
  const int lane = tid & 63, wave = tid >> 6;
  const int quad = lane >> 4, l15 = lane & 15;
  const int u = 15 - blockIdx.x;        // heavy tiles dispatch first
  const int h = blockIdx.y, hk = h >> 2;
  const int swz = 2 * (l15 & 7);        // even XOR swizzle for Pt groups

  // Q fragments as B-operand: qf[n][ks], n-tile qrow = u*128 + wave*32 + n*16 + l15
  bf16x8 qf[2][4];
#pragma unroll
  for (int n = 0; n < 2; ++n) {
    const u16* qrow = Qb + (long)(u * 128 + wave * 32 + n * 16 + l15) * (HQ * HD)
                      + h * HD + quad * 8;
#pragma unroll
    for (int ks = 0; ks < 4; ++ks) qf[n][ks] = *(const bf16x8*)(qrow + ks * 32);
  }

  float m_run[2] = {NEG_INF, NEG_INF}, l_run[2] = {0.f, 0.f};
  f32x4 oacc[8][2] = {};

  for (int j = 0; j <= u; ++j) {
    // ---- stage K (kpos rows) and V^T (d rows), row&15 XOR swizzle ----
#pragma unroll
    for (int it = 0; it < 8; ++it) {
      int c = tid + it * 256;           // 2048 chunks each
      int row = c >> 4, cc = c & 15, csrc = cc ^ (row & 15);
      async_load16(Kb + (long)(j * 128 + row) * (HK * HD) + hk * HD + csrc * 8,
                   (u16*)Ks + c * 8);
      async_load16(Vt + (long)(hk * HD + row) * S_LEN + j * 128 + csrc * 8,
                   (u16*)Vs + c * 8);
    }
    __syncthreads();

    // ---- S^T = K @ Q^T : sc[tj][n], row=kpos(quad*4+r), col=qrow(l15) ----
    f32x4 sc[8][2] = {};
#pragma unroll
    for (int ks = 0; ks < 4; ++ks)
#pragma unroll
      for (int tj = 0; tj < 8; ++tj) {
        int row = tj * 16 + l15;
        bf16x8 kf = *(const bf16x8*)(Ks + row * 128 + (((ks * 4 + quad) ^ (row & 15)) * 8));
        sc[tj][0] = mfma16(kf, qf[0][ks], sc[tj][0]);
        sc[tj][1] = mfma16(kf, qf[1][ks], sc[tj][1]);
      }

    // ---- online softmax per n (kpos in-lane over tj,r; cross-quad via 2 shuffles) ----
    const bool diag = (j == u);
#pragma unroll
    for (int n = 0; n < 2; ++n) {
      int qloc = wave * 32 + n * 16 + l15;     // local q row within tile
      if (diag) {
#pragma unroll
        for (int tj = 0; tj < 8; ++tj)
#pragma unroll
          for (int r = 0; r < 4; ++r)
            if (tj * 16 + quad * 4 + r > qloc) sc[tj][n][r] = NEG_INF;
      }
      float m = NEG_INF;
#pragma unroll
      for (int tj = 0; tj < 8; ++tj)
#pragma unroll
        for (int r = 0; r < 4; ++r) m = fmaxf(m, sc[tj][n][r]);
      m = fmaxf(m, __shfl_xor(m, 16));
      m = fmaxf(m, __shfl_xor(m, 32));
      float mnew = fmaxf(m_run[n], m);
      float alpha = __expf(m_run[n] - mnew);
      m_run[n] = mnew;
      float rs = 0.f;
#pragma unroll
      for (int tj = 0; tj < 8; ++tj)
#pragma unroll
        for (int r = 0; r < 4; ++r) {
          float p = __expf(sc[tj][n][r] - mnew);
          sc[tj][n][r] = p;
          rs += p;
        }
      rs += __shfl_xor(rs, 16);
      rs += __shfl_xor(rs, 32);
      l_run[n] = l_run[n] * alpha + rs;
#pragma unroll
      for (int tj = 0; tj < 8; ++tj) oacc[tj][n] *= alpha;
    }

    // ---- P^T -> per-wave LDS (b64 writes), read back as B fragments (b128) ----
    u16* pw = &Pts[wave][0];
    bf16x8 pf0[4], pf1[4];
#pragma unroll
    for (int tj = 0; tj < 8; ++tj) {
      union { u32 w[2]; uint2 u2; } pk;
      pk.w[0] = pack2bf(sc[tj][0][0], sc[tj][0][1]);
      pk.w[1] = pack2bf(sc[tj][0][2], sc[tj][0][3]);
      *(uint2*)(pw + l15 * 128 + (((tj * 4 + quad) ^ swz) * 4)) = pk.u2;
    }
    __asm__ volatile("s_waitcnt lgkmcnt(0)" ::: "memory");
#pragma unroll
    for (int ks = 0; ks < 4; ++ks)
      pf0[ks] = *(const bf16x8*)(pw + l15 * 128 + (((ks * 8 + quad * 2) ^ swz) * 4));
    __asm__ volatile("s_waitcnt lgkmcnt(0)" ::: "memory");
#pragma unroll
    for (int tj = 0; tj < 8; ++tj) {
      union { u32 w[2]; uint2 u2; } pk;
      pk.w[0] = pack2bf(sc[tj][1][0], sc[tj][1][1]);
      pk.w[1] = pack2bf(sc[tj][1][2], sc[tj][1][3]);
      *(uint2*)(pw + l15 * 128 + (((tj * 4 + quad) ^ swz) * 4)) = pk.u2;
    }
    __asm__ volatile("s_waitcnt lgkmcnt(0)" ::: "memory");
#pragma unroll
    for (int ks = 0; ks < 4; ++ks)
      pf1[ks] = *(const bf16x8*)(pw + l15 * 128 + (((ks * 8 + quad * 2) ^ swz) * 4));

    // ---- O^T += V^T @ P^T ----
#pragma unroll
    for (int ks = 0; ks < 4; ++ks)
#pragma unroll
      for (int tj = 0; tj < 8; ++tj) {
        int row = tj * 16 + l15;
        bf16x8 vf = *(const bf16x8*)(Vs + row * 128 + (((ks * 4 + quad) ^ (row & 15)) * 8));
        oacc[tj][0] = mfma16(vf, pf0[ks], oacc[tj][0]);
        oacc[tj][1] = mfma16(vf, pf1[ks], oacc[tj][1]);
      }
    __syncthreads();   // all waves done with Ks/Vs before next stage
  }

  // ---- epilogue: O^T tile row=d(quad*4+r), col=qrow(l15); pack 4 bf16 -> 8B store ----
#pragma unroll
  for (int n = 0; n < 2; ++n) {
    float inv_l = 1.0f / l_run[n];
    long grow = u * 128 + wave * 32 + n * 16 + l15;
#pragma unroll
    for (int tj = 0; tj < 8; ++tj) {
      int gcol = h * HD + tj * 16 + quad * 4;
      union { u32 w[2]; uint2 u2; } pk;
      pk.w[0] = pack2bf(oacc[tj][n][0] * inv_l, oacc[tj][n][1] * inv_l);
      pk.w[1] = pack2bf(oacc[tj][n][2] * inv_l, oacc[tj][n][3] * inv_l);
      *(uint2*)(Ob + grow * (HQ * HD) + gcol) = pk.u2;
    }
  }
}

// ---------- host ----------
#define MB (1024L * 1024L)

extern "C" void kernel_launch(void* const* d_in, const int* in_sizes, int n_in,
                              void* d_out, int out_size, void* d_ws, size_t ws_size,
                              hipStream_t stream) {
  const float* x    = (const float*)d_in[0];
  const float* fcos = (const float*)d_in[1];
  const float* fsin = (const float*)d_in[2];
  const float* wq   = (const float*)d_in[3];
  const float* wk   = (const float*)d_in[4];
  const float* wv   = (const float*)d_in[5];
  const float* wo   = (const float*)d_in[6];
  float* out = (float*)d_out;

  char* ws = (char*)d_ws;
  u16* wt    = (u16*)(ws + 0 * MB);     // 48 MB: QKV weights^T (6144,4096); reused for wo^T
  u16* xb    = (u16*)(ws + 48 * MB);    // 16 MB
  u16* QKVb  = (u16*)(ws + 64 * MB);    // 24 MB: (S, 6144) bf16
  u16* Qb    = (u16*)(ws + 88 * MB);    // 16 MB
  u16* Kb    = (u16*)(ws + 104 * MB);   // 4 MB
  u16* Vt    = (u16*)(ws + 108 * MB);   // 4 MB
  u16* attnb = (u16*)(ws + 112 * MB);   // 16 MB

  const int M = S_LEN, D = D_MODEL;

  // x -> bf16
  cvt_f32_bf16<<<(M * D) / 1024, 256, 0, stream>>>(x, xb, M * D);

  // weights^T (concat rows: wq^T | wk^T | wv^T)
  transpose_f32_bf16<<<dim3(D / 32, D / 32), dim3(32, 8), 0, stream>>>(wq, wt, D, HQ * HD);
  transpose_f32_bf16<<<dim3((HK * HD) / 32, D / 32), dim3(32, 8), 0, stream>>>(
      wk, wt + (long)(HQ * HD) * D, D, HK * HD);
  transpose_f32_bf16<<<dim3((HK * HD) / 32, D / 32), dim3(32, 8), 0, stream>>>(
      wv, wt + (long)(HQ * HD + HK * HD) * D, D, HK * HD);

  // fused QKV projection -> bf16
  gemm_bt_bf16<<<dim3(NQKV / 128, M / 128), 256, 0, stream>>>(xb, wt, QKVb, M, NQKV, D);

  // RoPE (scale folded into Q) from QKV slices
  rope_bf16<<<(M * HQ * 64) / 256, 256, 0, stream>>>(
      QKVb, fcos, fsin, Qb, HQ, NQKV, 0, 0.08838834764831845f);
  rope_bf16<<<(M * HK * 64) / 256, 256, 0, stream>>>(
      QKVb, fcos, fsin, Kb, HK, NQKV, HQ * HD, 1.0f);
  // V^T from QKV slice
  transpose_bf16<<<dim3((HK * HD) / 32, M / 32), dim3(32, 8), 0, stream>>>(
      QKVb, Vt, M, HK * HD, NQKV, HQ * HD + HK * HD);

  // flash attention
  attn_fwd<<<dim3(16, HQ), 256, 0, stream>>>(Qb, Kb, Vt, attnb);

  // out = attn @ wo
  transpose_f32_bf16<<<dim3(D / 32, D / 32), dim3(32, 8), 0, stream>>>(wo, wt, HQ * HD, D);
  gemm_bt<<<dim3(D / 128, M / 128), 256, 0, stream>>>(attnb, wt, out, M, D, HQ * HD);
}